// Round 2
// baseline (449.775 us; speedup 1.0000x reference)
//
#include <hip/hip_runtime.h>
#include <stdint.h>
#include <stddef.h>

typedef __attribute__((ext_vector_type(4))) float f32x4;
typedef __attribute__((ext_vector_type(8))) short s16x8;
typedef __attribute__((ext_vector_type(4))) short s16x4;

// ---------- helpers ----------
__device__ __forceinline__ short f2bf(float f) {
  uint32_t u = __builtin_bit_cast(uint32_t, f);
  uint32_t r = (u + 0x7fffu + ((u >> 16) & 1u)) >> 16;
  return (short)r;
}

__device__ __forceinline__ void gload_lds16(const void* g, void* l) {
  __builtin_amdgcn_global_load_lds(
      (const __attribute__((address_space(1))) void*)g,
      (__attribute__((address_space(3))) void*)l, 16, 0, 0);
}

// Row-function swizzle mask (in units of 8 shorts = 16B slots)
__device__ __forceinline__ int msk8(int r) { return (r & 7) ^ ((r >> 3) & 7); }
// LDS index (shorts) for row r, short-col c, row stride 64 shorts, XOR swizzle
__device__ __forceinline__ int swz(int r, int c) {
  return r * 64 + (c ^ (msk8(r) << 3));
}

// ---------- fp32 -> bf16 convert ----------
__global__ __launch_bounds__(256) void cvt_kernel(const float* __restrict__ src,
                                                  short* __restrict__ dst, int n4) {
  int i = blockIdx.x * blockDim.x + threadIdx.x;
  if (i >= n4) return;
  float4 v = reinterpret_cast<const float4*>(src)[i];
  s16x4 o;
  o[0] = f2bf(v.x); o[1] = f2bf(v.y); o[2] = f2bf(v.z); o[3] = f2bf(v.w);
  reinterpret_cast<s16x4*>(dst)[i] = o;
}

// ---------- GEMM: C[M,N] = A[M,K] * B[N,K]^T  (both row-major, K contiguous) ----------
// 128x128 tile, BK=64, 4 waves (2x2), each wave 64x64 via 4x4 frags of 16x16x32 MFMA.
template <int OUTF32>
__global__ __launch_bounds__(256) void gemm_bt(const short* __restrict__ A,
                                               const short* __restrict__ B,
                                               void* __restrict__ Cv,
                                               const float* __restrict__ bias,
                                               int M, int N, int K) {
  __shared__ short lA[128 * 64];
  __shared__ short lB[128 * 64];
  const int tid = threadIdx.x;
  const int lane = tid & 63, wid = tid >> 6;
  const int g = lane >> 4, li = lane & 15;
  const int nbx = N >> 7;
  const int by = blockIdx.x / nbx, bx = blockIdx.x % nbx;
  const int brow = by << 7, bcol = bx << 7;
  const int wr = (wid >> 1) << 6, wc = (wid & 1) << 6;

  f32x4 acc[4][4] = {};

  for (int k0 = 0; k0 < K; k0 += 64) {
    __syncthreads();
#pragma unroll
    for (int i = 0; i < 4; i++) {  // stage A tile 128x64 (16KB)
      int j = tid + i * 256;
      int r = j >> 3, s = j & 7;
      gload_lds16(A + (size_t)(brow + r) * K + k0 + 8 * (s ^ msk8(r)), &lA[j * 8]);
    }
#pragma unroll
    for (int i = 0; i < 4; i++) {  // stage B tile 128x64
      int j = tid + i * 256;
      int r = j >> 3, s = j & 7;
      gload_lds16(B + (size_t)(bcol + r) * K + k0 + 8 * (s ^ msk8(r)), &lB[j * 8]);
    }
    __syncthreads();
#pragma unroll
    for (int ks = 0; ks < 2; ks++) {
      s16x8 af[4], bfr[4];
#pragma unroll
      for (int ai = 0; ai < 4; ai++) {
        int row = wr + ai * 16 + li;
        af[ai] = *(const s16x8*)&lA[swz(row, ks * 32 + g * 8)];
      }
#pragma unroll
      for (int bj = 0; bj < 4; bj++) {
        int row = wc + bj * 16 + li;
        bfr[bj] = *(const s16x8*)&lB[swz(row, ks * 32 + g * 8)];
      }
#pragma unroll
      for (int ai = 0; ai < 4; ai++)
#pragma unroll
        for (int bj = 0; bj < 4; bj++)
          acc[ai][bj] = __builtin_amdgcn_mfma_f32_16x16x32_bf16(af[ai], bfr[bj],
                                                               acc[ai][bj], 0, 0, 0);
    }
  }

#pragma unroll
  for (int ai = 0; ai < 4; ai++) {
#pragma unroll
    for (int bj = 0; bj < 4; bj++) {
#pragma unroll
      for (int e = 0; e < 4; e++) {
        int row = brow + wr + ai * 16 + g * 4 + e;  // C/D: col=lane&15, row=(lane>>4)*4+e
        int col = bcol + wc + bj * 16 + li;
        float v = acc[ai][bj][e];
        if (OUTF32) {
          ((float*)Cv)[(size_t)row * N + col] = v + bias[col];
        } else {
          ((short*)Cv)[(size_t)row * N + col] = f2bf(v);
        }
      }
    }
  }
}

// ---------- flash attention ----------
// qkv: [8192][3072] bf16 (q | k | v, each head*64 wide). One block per
// (b, head, 64-row q-tile). 4 waves; wave owns 16 q-rows, all keys.
__global__ __launch_bounds__(256) void attn_kernel(const short* __restrict__ qkv,
                                                   short* __restrict__ aout) {
  __shared__ short lQ[64 * 64];
  __shared__ short lK[64 * 64];
  __shared__ short lVt[64 * 64];
  __shared__ short lP[4][16 * 64];

  const int tid = threadIdx.x;
  const int lane = tid & 63, w = tid >> 6;
  const int g = lane >> 4, li = lane & 15;
  const int bid = blockIdx.x;
  const int qt = bid & 31, head = (bid >> 5) & 15, b = bid >> 9;
  const int row0 = b * 2048;
  const int qbase = qt * 64;
  const int qcol = head * 64, kcol = 1024 + head * 64, vcol = 2048 + head * 64;

  // stage Q tile once (64x64)
#pragma unroll
  for (int i = 0; i < 2; i++) {
    int j = tid + i * 256;
    int r = j >> 3, s = j & 7;
    gload_lds16(qkv + (size_t)(row0 + qbase + r) * 3072 + qcol + 8 * (s ^ msk8(r)),
                &lQ[j * 8]);
  }

  f32x4 acc_o[4] = {};
  float m_r[4], l_r[4];
#pragma unroll
  for (int e = 0; e < 4; e++) { m_r[e] = -1e30f; l_r[e] = 0.f; }

  for (int jt = 0; jt < 32; jt++) {
    const int jbase = jt * 64;
    __syncthreads();  // previous compute done before overwriting K/Vt
    // stage K tile (64x64) via global_load_lds, source pre-swizzled
#pragma unroll
    for (int i = 0; i < 2; i++) {
      int j = tid + i * 256;
      int r = j >> 3, s = j & 7;
      gload_lds16(qkv + (size_t)(row0 + jbase + r) * 3072 + kcol + 8 * (s ^ msk8(r)),
                  &lK[j * 8]);
    }
    // stage V transposed: Vt[d][j], coalesced global reads, swizzled LDS writes
#pragma unroll
    for (int i = 0; i < 2; i++) {
      int sl = tid + i * 256;
      int j = sl >> 3, d0 = (sl & 7) * 8;
      s16x8 v = *(const s16x8*)(qkv + (size_t)(row0 + jbase + j) * 3072 + vcol + d0);
#pragma unroll
      for (int e = 0; e < 8; e++) lVt[swz(d0 + e, j)] = v[e];
    }
    __syncthreads();

    // Q A-frags (2 ksubs over d=64)
    s16x8 qf[2];
#pragma unroll
    for (int ks = 0; ks < 2; ks++) {
      int row = w * 16 + li;
      qf[ks] = *(const s16x8*)&lQ[swz(row, ks * 32 + g * 8)];
    }

    // S = (Q*scale)(K*scale)^T  -> apply 1/sqrt(d)=0.125 once on S
    f32x4 s_acc[4];
#pragma unroll
    for (int bj = 0; bj < 4; bj++) {
      int row = bj * 16 + li;
      s16x8 kf0 = *(const s16x8*)&lK[swz(row, g * 8)];
      s16x8 kf1 = *(const s16x8*)&lK[swz(row, 32 + g * 8)];
      f32x4 z = {};
      z = __builtin_amdgcn_mfma_f32_16x16x32_bf16(qf[0], kf0, z, 0, 0, 0);
      z = __builtin_amdgcn_mfma_f32_16x16x32_bf16(qf[1], kf1, z, 0, 0, 0);
      s_acc[bj] = z * 0.125f;
    }

    // online softmax; row r=g*4+e lives in 16-lane group g (cols bj*16+li)
    float p[4][4], mnew[4], alpha[4];
#pragma unroll
    for (int e = 0; e < 4; e++) {
      float rm = fmaxf(fmaxf(s_acc[0][e], s_acc[1][e]),
                       fmaxf(s_acc[2][e], s_acc[3][e]));
#pragma unroll
      for (int off = 1; off < 16; off <<= 1) rm = fmaxf(rm, __shfl_xor(rm, off, 64));
      mnew[e] = fmaxf(m_r[e], rm);
      alpha[e] = __expf(m_r[e] - mnew[e]);
      m_r[e] = mnew[e];
    }
#pragma unroll
    for (int bj = 0; bj < 4; bj++)
#pragma unroll
      for (int e = 0; e < 4; e++) p[bj][e] = __expf(s_acc[bj][e] - mnew[e]);
#pragma unroll
    for (int e = 0; e < 4; e++) {
      float rs = p[0][e] + p[1][e] + p[2][e] + p[3][e];
#pragma unroll
      for (int off = 1; off < 16; off <<= 1) rs += __shfl_xor(rs, off, 64);
      l_r[e] = l_r[e] * alpha[e] + rs;
      acc_o[0][e] *= alpha[e]; acc_o[1][e] *= alpha[e];
      acc_o[2][e] *= alpha[e]; acc_o[3][e] *= alpha[e];
    }

    // P -> LDS (acc layout -> A-frag layout), per-wave buffer
#pragma unroll
    for (int bj = 0; bj < 4; bj++)
#pragma unroll
      for (int e = 0; e < 4; e++) {
        int row = g * 4 + e;
        lP[w][swz(row, bj * 16 + li)] = f2bf(p[bj][e]);
      }
    __syncthreads();  // P visible; Vt still valid until loop-top sync

    // O += P * V
    s16x8 pf[2];
#pragma unroll
    for (int g2 = 0; g2 < 2; g2++)
      pf[g2] = *(const s16x8*)&lP[w][swz(li, g2 * 32 + g * 8)];
#pragma unroll
    for (int f = 0; f < 4; f++) {
      int row = f * 16 + li;
      s16x8 v0 = *(const s16x8*)&lVt[swz(row, g * 8)];
      s16x8 v1 = *(const s16x8*)&lVt[swz(row, 32 + g * 8)];
      acc_o[f] = __builtin_amdgcn_mfma_f32_16x16x32_bf16(pf[0], v0, acc_o[f], 0, 0, 0);
      acc_o[f] = __builtin_amdgcn_mfma_f32_16x16x32_bf16(pf[1], v1, acc_o[f], 0, 0, 0);
    }
  }

  // epilogue: O /= l, write bf16 a[8192][1024]
#pragma unroll
  for (int f = 0; f < 4; f++)
#pragma unroll
    for (int e = 0; e < 4; e++) {
      int row = row0 + qbase + w * 16 + g * 4 + e;
      int col = head * 64 + f * 16 + li;
      aout[(size_t)row * 1024 + col] = f2bf(acc_o[f][e] / l_r[e]);
    }
}

// ---------- launch ----------
extern "C" void kernel_launch(void* const* d_in, const int* in_sizes, int n_in,
                              void* d_out, int out_size, void* d_ws, size_t ws_size,
                              hipStream_t stream) {
  const float* x    = (const float*)d_in[0];
  const float* Wq   = (const float*)d_in[1];
  const float* Wk   = (const float*)d_in[2];
  const float* Wv   = (const float*)d_in[3];
  const float* Wout = (const float*)d_in[4];
  const float* bout = (const float*)d_in[5];
  float* out = (float*)d_out;

  char* ws = (char*)d_ws;
  short* xb    = (short*)(ws);                        // 16 MB  [8192][1024]
  short* Wqkv  = (short*)(ws + (16ull << 20));        //  6 MB  [3072][1024]
  short* Woutb = (short*)(ws + (22ull << 20));        //  2 MB  [1024][1024]
  short* qkv   = (short*)(ws + (24ull << 20));        // 48 MB  [8192][3072]
  short* a_ws  = xb;                                  // alias: xb dead after GEMM1

  // fp32 -> bf16
  cvt_kernel<<<8192, 256, 0, stream>>>(x, xb, 2097152);
  cvt_kernel<<<1024, 256, 0, stream>>>(Wq, Wqkv, 262144);
  cvt_kernel<<<1024, 256, 0, stream>>>(Wk, Wqkv + 1048576, 262144);
  cvt_kernel<<<1024, 256, 0, stream>>>(Wv, Wqkv + 2097152, 262144);
  cvt_kernel<<<1024, 256, 0, stream>>>(Wout, Woutb, 262144);

  // qkv = xb @ [Wq;Wk;Wv]^T   (M=8192, N=3072, K=1024)
  gemm_bt<0><<<64 * 24, 256, 0, stream>>>(xb, Wqkv, qkv, nullptr, 8192, 3072, 1024);

  // attention: 4 batches * 16 heads * 32 q-tiles
  attn_kernel<<<2048, 256, 0, stream>>>(qkv, a_ws);

  // out = a @ Wout^T + bout   (M=8192, N=1024, K=1024), fp32 out
  gemm_bt<1><<<64 * 8, 256, 0, stream>>>(a_ws, Woutb, out, bout, 8192, 1024, 1024);
}

// Round 4
// 318.798 us; speedup vs baseline: 1.4108x; 1.4108x over previous
//
#include <hip/hip_runtime.h>
#include <stdint.h>
#include <stddef.h>

typedef __attribute__((ext_vector_type(4))) float f32x4;
typedef __attribute__((ext_vector_type(16))) float f32x16;
typedef __attribute__((ext_vector_type(8))) short s16x8;
typedef __attribute__((ext_vector_type(4))) short s16x4;

// ---------- helpers ----------
__device__ __forceinline__ short f2bf(float f) {
  uint32_t u = __builtin_bit_cast(uint32_t, f);
  uint32_t r = (u + 0x7fffu + ((u >> 16) & 1u)) >> 16;
  return (short)r;
}

__device__ __forceinline__ void gload_lds16(const void* g, void* l) {
  __builtin_amdgcn_global_load_lds(
      (const __attribute__((address_space(1))) void*)g,
      (__attribute__((address_space(3))) void*)l, 16, 0, 0);
}

// Row-function swizzle mask (in units of 8 shorts = 16B slots)
__device__ __forceinline__ int msk8(int r) { return (r & 7) ^ ((r >> 3) & 7); }
__device__ __forceinline__ int swz(int r, int c) {
  return r * 64 + (c ^ (msk8(r) << 3));
}

// ---------- fp32 -> bf16 convert ----------
__global__ __launch_bounds__(256) void cvt_kernel(const float* __restrict__ src,
                                                  short* __restrict__ dst, int n4) {
  int i = blockIdx.x * blockDim.x + threadIdx.x;
  if (i >= n4) return;
  float4 v = reinterpret_cast<const float4*>(src)[i];
  s16x4 o;
  o[0] = f2bf(v.x); o[1] = f2bf(v.y); o[2] = f2bf(v.z); o[3] = f2bf(v.w);
  reinterpret_cast<s16x4*>(dst)[i] = o;
}

// ---------- GEMM: C[M,N] = A[M,K] * B[N,K]^T (unchanged from round 2) ----------
template <int OUTF32>
__global__ __launch_bounds__(256) void gemm_bt(const short* __restrict__ A,
                                               const short* __restrict__ B,
                                               void* __restrict__ Cv,
                                               const float* __restrict__ bias,
                                               int M, int N, int K) {
  __shared__ short lA[128 * 64];
  __shared__ short lB[128 * 64];
  const int tid = threadIdx.x;
  const int lane = tid & 63, wid = tid >> 6;
  const int g = lane >> 4, li = lane & 15;
  const int nbx = N >> 7;
  const int by = blockIdx.x / nbx, bx = blockIdx.x % nbx;
  const int brow = by << 7, bcol = bx << 7;
  const int wr = (wid >> 1) << 6, wc = (wid & 1) << 6;

  f32x4 acc[4][4] = {};

  for (int k0 = 0; k0 < K; k0 += 64) {
    __syncthreads();
#pragma unroll
    for (int i = 0; i < 4; i++) {
      int j = tid + i * 256;
      int r = j >> 3, s = j & 7;
      gload_lds16(A + (size_t)(brow + r) * K + k0 + 8 * (s ^ msk8(r)), &lA[j * 8]);
    }
#pragma unroll
    for (int i = 0; i < 4; i++) {
      int j = tid + i * 256;
      int r = j >> 3, s = j & 7;
      gload_lds16(B + (size_t)(bcol + r) * K + k0 + 8 * (s ^ msk8(r)), &lB[j * 8]);
    }
    __syncthreads();
#pragma unroll
    for (int ks = 0; ks < 2; ks++) {
      s16x8 af[4], bfr[4];
#pragma unroll
      for (int ai = 0; ai < 4; ai++) {
        int row = wr + ai * 16 + li;
        af[ai] = *(const s16x8*)&lA[swz(row, ks * 32 + g * 8)];
      }
#pragma unroll
      for (int bj = 0; bj < 4; bj++) {
        int row = wc + bj * 16 + li;
        bfr[bj] = *(const s16x8*)&lB[swz(row, ks * 32 + g * 8)];
      }
#pragma unroll
      for (int ai = 0; ai < 4; ai++)
#pragma unroll
        for (int bj = 0; bj < 4; bj++)
          acc[ai][bj] = __builtin_amdgcn_mfma_f32_16x16x32_bf16(af[ai], bfr[bj],
                                                               acc[ai][bj], 0, 0, 0);
    }
  }

#pragma unroll
  for (int ai = 0; ai < 4; ai++) {
#pragma unroll
    for (int bj = 0; bj < 4; bj++) {
#pragma unroll
      for (int e = 0; e < 4; e++) {
        int row = brow + wr + ai * 16 + g * 4 + e;
        int col = bcol + wc + bj * 16 + li;
        float v = acc[ai][bj][e];
        if (OUTF32) {
          ((float*)Cv)[(size_t)row * N + col] = v + bias[col];
        } else {
          ((short*)Cv)[(size_t)row * N + col] = f2bf(v);
        }
      }
    }
  }
}

// ---------- flash attention, swapped-QK^T 32x32 in-register-softmax ----------
// qkv: [8192][3072] bf16. Block = 256 thr = 4 waves; wave owns 32 q-rows.
// Grid: 4 b * 16 heads * 16 q-tiles(128 rows) = 1024 blocks. KVBLK = 32.
//
// Frag-major LDS: K blocks (step s=0..3): lane l holds K[k=l&31][16s+8*(l>>5)+e].
// V blocks (ks,dd): logical slot lf=(d&31)|(k-half<<5) holds V^T[d][16ks+8hi+e],
// stored at slot lf ^ ((lf>>3)&7) (XOR involution -> conflict-free r/w).
__global__ __launch_bounds__(256, 3) void attn_kernel(const short* __restrict__ qkv,
                                                      short* __restrict__ aout) {
  __shared__ short lQ[4 * 4 * 512];   // 16KB: wave w, step s
  __shared__ short lK[4 * 512];       //  4KB: step s
  __shared__ short lV[4 * 512];       //  4KB: block ks*2+dd

  const int tid = threadIdx.x;
  const int lane = tid & 63, w = tid >> 6;
  const int l31 = lane & 31, hi = lane >> 5;
  const int bid = blockIdx.x;
  const int qt = bid & 15, head = (bid >> 4) & 15, b = bid >> 8;
  const int row0 = b * 2048;
  const int qrow = qt * 128 + w * 32 + l31;
  const int qcol = head * 64, kcol = 1024 + head * 64, vcol = 2048 + head * 64;

  // stage Q frag-major (per-lane global source, linear LDS dest)
#pragma unroll
  for (int s = 0; s < 4; s++)
    gload_lds16(qkv + (size_t)(row0 + qrow) * 3072 + qcol + 16 * s + 8 * hi,
                &lQ[(w * 4 + s) * 512]);
  __syncthreads();
  s16x8 qf[4];
#pragma unroll
  for (int s = 0; s < 4; s++)
    qf[s] = *(const s16x8*)&lQ[(w * 4 + s) * 512 + lane * 8];

  // V staging decode (thread reads V[vj][8*va .. +8])
  const int vj = tid >> 3, va = tid & 7;
  const int vdd = va >> 2, va3 = va & 3;
  const int vhi = (vj >> 3) & 1, vks = vj >> 4, vef = vj & 7;
  const int vblk = (vks * 2 + vdd) * 512;
  const int vxor = va3 | (vhi << 2);
  const int vslot_r = (lane ^ ((lane >> 3) & 7)) * 8;  // read slot (lane-permutation)

  f32x16 acc0 = {}, acc1 = {};
  float m2 = -1e30f, l_r = 0.f;
  const float SCL = 0.125f * 1.44269504088896f;   // exp2 domain
  const float THR = 8.f * 1.44269504088896f;      // defer-max threshold (e^8)

  for (int jt = 0; jt < 64; jt++) {
    const int jbase = jt * 32;
    // early V global read (no LDS dependency -> overlaps prev tile's PV)
    s16x8 vstage =
        *(const s16x8*)(qkv + (size_t)(row0 + jbase + vj) * 3072 + vcol + 8 * va);
    __syncthreads();  // prev tile's LDS reads done
    // K frag-major stage: wave w stages step w
    gload_lds16(qkv + (size_t)(row0 + jbase + l31) * 3072 + kcol + 16 * w + 8 * hi,
                &lK[w * 512]);
    // V scatter into swizzled frag-major layout
#pragma unroll
    for (int t2 = 0; t2 < 8; t2++) {
      int slot = 32 * vhi + 8 * va3 + (t2 ^ vxor);
      lV[vblk + slot * 8 + vef] = vstage[t2];
    }
    __syncthreads();

    // S^T[k][q] = mfma(K, Q): col=lane&31=q, key=(r&3)+8*(r>>2)+4*hi
    f32x16 st = {};
#pragma unroll
    for (int s = 0; s < 4; s++) {
      s16x8 kf = *(const s16x8*)&lK[s * 512 + lane * 8];
      st = __builtin_amdgcn_mfma_f32_32x32x16_bf16(kf, qf[s], st, 0, 0, 0);
    }

    // in-register online softmax (q = lane&31; halves combined via shfl_xor 32)
    float scl[16];
#pragma unroll
    for (int r = 0; r < 16; r++) scl[r] = st[r] * SCL;
    float pm = scl[0];
#pragma unroll
    for (int r = 1; r < 16; r++) pm = fmaxf(pm, scl[r]);
    pm = fmaxf(pm, __shfl_xor(pm, 32, 64));
    if (__any(pm > m2 + THR)) {     // defer-max (T13)
      float mn = fmaxf(m2, pm);
      float al = exp2f(m2 - mn);
      m2 = mn;
      l_r *= al;
#pragma unroll
      for (int r = 0; r < 16; r++) { acc0[r] *= al; acc1[r] *= al; }
    }
    float p[16];
    float rs = 0.f;
#pragma unroll
    for (int r = 0; r < 16; r++) { p[r] = exp2f(scl[r] - m2); rs += p[r]; }
    rs += __shfl_xor(rs, 32, 64);
    l_r += rs;

    // P -> bf16 B-frags in-register. Lane (hi) owns keys 16ks+4hi+{0..3} (x0,x1)
    // and 16ks+8+4hi+{0..3} (y0,y1); B-frag wants keys 16ks+8hi+{0..7}.
    // Cross-half exchange via shfl_xor(32) + select (semantically exact).
#pragma unroll
    for (int ks = 0; ks < 2; ks++) {
      int x0, x1, y0, y1;
      asm("v_cvt_pk_bf16_f32 %0, %1, %2" : "=v"(x0) : "v"(p[8*ks+0]), "v"(p[8*ks+1]));
      asm("v_cvt_pk_bf16_f32 %0, %1, %2" : "=v"(x1) : "v"(p[8*ks+2]), "v"(p[8*ks+3]));
      asm("v_cvt_pk_bf16_f32 %0, %1, %2" : "=v"(y0) : "v"(p[8*ks+4]), "v"(p[8*ks+5]));
      asm("v_cvt_pk_bf16_f32 %0, %1, %2" : "=v"(y1) : "v"(p[8*ks+6]), "v"(p[8*ks+7]));
      int sx0 = __shfl_xor(x0, 32, 64);
      int sx1 = __shfl_xor(x1, 32, 64);
      int sy0 = __shfl_xor(y0, 32, 64);
      int sy1 = __shfl_xor(y1, 32, 64);
      int4 paw;
      paw.x = hi ? sy0 : x0;   // keys 16ks+8hi+{0,1}
      paw.y = hi ? sy1 : x1;   // keys 16ks+8hi+{2,3}
      paw.z = hi ? y0 : sx0;   // keys 16ks+8hi+{4,5}
      paw.w = hi ? y1 : sx1;   // keys 16ks+8hi+{6,7}
      s16x8 pa = __builtin_bit_cast(s16x8, paw);
      s16x8 v0 = *(const s16x8*)&lV[(ks * 2 + 0) * 512 + vslot_r];
      s16x8 v1 = *(const s16x8*)&lV[(ks * 2 + 1) * 512 + vslot_r];
      acc0 = __builtin_amdgcn_mfma_f32_32x32x16_bf16(v0, pa, acc0, 0, 0, 0);
      acc1 = __builtin_amdgcn_mfma_f32_32x32x16_bf16(v1, pa, acc1, 0, 0, 0);
    }
  }

  // epilogue: O[q][d] = O^T / l ; per lane q = l31 fixed, scatter cols
  float inv = 1.f / l_r;
  const size_t rowoff = (size_t)(row0 + qt * 128 + w * 32 + l31) * 1024 + head * 64;
#pragma unroll
  for (int r = 0; r < 16; r++) {
    int dbase = (r & 3) + 8 * (r >> 2) + 4 * hi;
    aout[rowoff + dbase] = f2bf(acc0[r] * inv);
    aout[rowoff + 32 + dbase] = f2bf(acc1[r] * inv);
  }
}

// ---------- launch ----------
extern "C" void kernel_launch(void* const* d_in, const int* in_sizes, int n_in,
                              void* d_out, int out_size, void* d_ws, size_t ws_size,
                              hipStream_t stream) {
  const float* x    = (const float*)d_in[0];
  const float* Wq   = (const float*)d_in[1];
  const float* Wk   = (const float*)d_in[2];
  const float* Wv   = (const float*)d_in[3];
  const float* Wout = (const float*)d_in[4];
  const float* bout = (const float*)d_in[5];
  float* out = (float*)d_out;

  char* ws = (char*)d_ws;
  short* xb    = (short*)(ws);                        // 16 MB  [8192][1024]
  short* Wqkv  = (short*)(ws + (16ull << 20));        //  6 MB  [3072][1024]
  short* Woutb = (short*)(ws + (22ull << 20));        //  2 MB  [1024][1024]
  short* qkv   = (short*)(ws + (24ull << 20));        // 48 MB  [8192][3072]
  short* a_ws  = xb;                                  // alias: xb dead after GEMM1

  // fp32 -> bf16
  cvt_kernel<<<8192, 256, 0, stream>>>(x, xb, 2097152);
  cvt_kernel<<<1024, 256, 0, stream>>>(Wq, Wqkv, 262144);
  cvt_kernel<<<1024, 256, 0, stream>>>(Wk, Wqkv + 1048576, 262144);
  cvt_kernel<<<1024, 256, 0, stream>>>(Wv, Wqkv + 2097152, 262144);
  cvt_kernel<<<1024, 256, 0, stream>>>(Wout, Woutb, 262144);

  // qkv = xb @ [Wq;Wk;Wv]^T   (M=8192, N=3072, K=1024)
  gemm_bt<0><<<64 * 24, 256, 0, stream>>>(xb, Wqkv, qkv, nullptr, 8192, 3072, 1024);

  // attention: 4 b * 16 heads * 16 q-tiles
  attn_kernel<<<1024, 256, 0, stream>>>(qkv, a_ws);

  // out = a @ Wout^T + bout   (M=8192, N=1024, K=1024), fp32 out
  gemm_bt<1><<<64 * 8, 256, 0, stream>>>(a_ws, Woutb, out, bout, 8192, 1024, 1024);
}

// Round 5
// 300.287 us; speedup vs baseline: 1.4978x; 1.0616x over previous
//
#include <hip/hip_runtime.h>
#include <stdint.h>
#include <stddef.h>

typedef __attribute__((ext_vector_type(4))) float f32x4;
typedef __attribute__((ext_vector_type(16))) float f32x16;
typedef __attribute__((ext_vector_type(8))) short s16x8;
typedef __attribute__((ext_vector_type(4))) short s16x4;
typedef __attribute__((ext_vector_type(2))) int i32x2;

// ---------- helpers ----------
__device__ __forceinline__ short f2bf(float f) {
  uint32_t u = __builtin_bit_cast(uint32_t, f);
  uint32_t r = (u + 0x7fffu + ((u >> 16) & 1u)) >> 16;
  return (short)r;
}

__device__ __forceinline__ void gload_lds16(const void* g, void* l) {
  __builtin_amdgcn_global_load_lds(
      (const __attribute__((address_space(1))) void*)g,
      (__attribute__((address_space(3))) void*)l, 16, 0, 0);
}

// Row-function swizzle mask (in units of 8 shorts = 16B slots)
__device__ __forceinline__ int msk8(int r) { return (r & 7) ^ ((r >> 3) & 7); }
__device__ __forceinline__ int swz(int r, int c) {
  return r * 64 + (c ^ (msk8(r) << 3));
}

// ---------- fp32 -> bf16 convert ----------
__global__ __launch_bounds__(256) void cvt_kernel(const float* __restrict__ src,
                                                  short* __restrict__ dst, int n4) {
  int i = blockIdx.x * blockDim.x + threadIdx.x;
  if (i >= n4) return;
  float4 v = reinterpret_cast<const float4*>(src)[i];
  s16x4 o;
  o[0] = f2bf(v.x); o[1] = f2bf(v.y); o[2] = f2bf(v.z); o[3] = f2bf(v.w);
  reinterpret_cast<s16x4*>(dst)[i] = o;
}

// ---------- GEMM: C[M,N] = A[M,K] * B[N,K]^T ----------
// 128x128 tile, BK=64, 4 waves. XCD-swizzled blockIdx (grid%8==0).
// Cols < qcols get scaled by qscl in f32 before the bf16 round (q pre-scale).
template <int OUTF32>
__global__ __launch_bounds__(256) void gemm_bt(const short* __restrict__ A,
                                               const short* __restrict__ B,
                                               void* __restrict__ Cv,
                                               const float* __restrict__ bias,
                                               int M, int N, int K,
                                               float qscl, int qcols) {
  __shared__ short lA[128 * 64];
  __shared__ short lB[128 * 64];
  const int tid = threadIdx.x;
  const int lane = tid & 63, wid = tid >> 6;
  const int g = lane >> 4, li = lane & 15;
  const int nbx = N >> 7;
  const int q8 = gridDim.x >> 3;
  const int orig = blockIdx.x;
  const int bswz = (orig & 7) * q8 + (orig >> 3);   // XCD-aware (T1), grid%8==0
  const int by = bswz / nbx, bx = bswz % nbx;
  const int brow = by << 7, bcol = bx << 7;
  const int wr = (wid >> 1) << 6, wc = (wid & 1) << 6;

  f32x4 acc[4][4] = {};

  for (int k0 = 0; k0 < K; k0 += 64) {
    __syncthreads();
#pragma unroll
    for (int i = 0; i < 4; i++) {
      int j = tid + i * 256;
      int r = j >> 3, s = j & 7;
      gload_lds16(A + (size_t)(brow + r) * K + k0 + 8 * (s ^ msk8(r)), &lA[j * 8]);
    }
#pragma unroll
    for (int i = 0; i < 4; i++) {
      int j = tid + i * 256;
      int r = j >> 3, s = j & 7;
      gload_lds16(B + (size_t)(bcol + r) * K + k0 + 8 * (s ^ msk8(r)), &lB[j * 8]);
    }
    __syncthreads();
#pragma unroll
    for (int ks = 0; ks < 2; ks++) {
      s16x8 af[4], bfr[4];
#pragma unroll
      for (int ai = 0; ai < 4; ai++) {
        int row = wr + ai * 16 + li;
        af[ai] = *(const s16x8*)&lA[swz(row, ks * 32 + g * 8)];
      }
#pragma unroll
      for (int bj = 0; bj < 4; bj++) {
        int row = wc + bj * 16 + li;
        bfr[bj] = *(const s16x8*)&lB[swz(row, ks * 32 + g * 8)];
      }
#pragma unroll
      for (int ai = 0; ai < 4; ai++)
#pragma unroll
        for (int bj = 0; bj < 4; bj++)
          acc[ai][bj] = __builtin_amdgcn_mfma_f32_16x16x32_bf16(af[ai], bfr[bj],
                                                               acc[ai][bj], 0, 0, 0);
    }
  }

#pragma unroll
  for (int ai = 0; ai < 4; ai++) {
#pragma unroll
    for (int bj = 0; bj < 4; bj++) {
#pragma unroll
      for (int e = 0; e < 4; e++) {
        int row = brow + wr + ai * 16 + g * 4 + e;
        int col = bcol + wc + bj * 16 + li;
        float v = acc[ai][bj][e];
        if (col < qcols) v *= qscl;
        if (OUTF32) {
          ((float*)Cv)[(size_t)row * N + col] = v + bias[col];
        } else {
          ((short*)Cv)[(size_t)row * N + col] = f2bf(v);
        }
      }
    }
  }
}

// ---------- flash attention: KVBLK=64, dbuf LDS, 1 barrier/iter ----------
// qkv: [8192][3072] bf16; q-columns pre-scaled by 0.125*log2(e) in GEMM1.
// Block = 4 waves; wave owns 32 q-rows. Grid: 4b*16h*16qt = 1024.
// Buffer (16KB = 8192 shorts): K frag blocks [sub(2)][s(4)]*512, then
// V frag blocks at +4096: [sub(2)]*2048 with [ks(2)][dd(2)]*512 inside.
__global__ __launch_bounds__(256, 4) void attn_kernel(const short* __restrict__ qkv,
                                                      short* __restrict__ aout) {
  __shared__ short lds[2][8192];   // 32KB double buffer

  const int tid = threadIdx.x;
  const int lane = tid & 63, w = tid >> 6;
  const int l31 = lane & 31, hi = lane >> 5;
  const int bid = blockIdx.x;
  const int qt = bid & 15, head = (bid >> 4) & 15, b = bid >> 8;
  const int row0 = b * 2048;
  const int qrow = qt * 128 + w * 32 + l31;
  const int qcol = head * 64, kcol = 1024 + head * 64, vcol = 2048 + head * 64;

  // ---- prologue: Q frags via transient LDS (buf0 region, reused after) ----
#pragma unroll
  for (int s = 0; s < 4; s++)
    gload_lds16(qkv + (size_t)(row0 + qrow) * 3072 + qcol + 16 * s + 8 * hi,
                &lds[0][(w * 4 + s) * 512]);
  __syncthreads();
  s16x8 qf[4];
#pragma unroll
  for (int s = 0; s < 4; s++)
    qf[s] = *(const s16x8*)&lds[0][(w * 4 + s) * 512 + lane * 8];
  __syncthreads();   // qf reads done before buf0 is overwritten

  // V staging decode (thread covers V[sub][vj][8va..+8])
  const int vj = tid >> 3, va = tid & 7;
  const int vdd = va >> 2, va3 = va & 3;
  const int vhi = (vj >> 3) & 1, vks = vj >> 4, vef = vj & 7;
  const int vblk = (vks * 2 + vdd) * 512;
  const int vxor = va3 | (vhi << 2);
  const int vslot_r = (lane ^ ((lane >> 3) & 7)) * 8;

  // stage tile 0 into buf0
#pragma unroll
  for (int sub = 0; sub < 2; sub++)
    gload_lds16(qkv + (size_t)(row0 + sub * 32 + l31) * 3072 + kcol + 16 * w + 8 * hi,
                &lds[0][(sub * 4 + w) * 512]);
#pragma unroll
  for (int sub = 0; sub < 2; sub++) {
    s16x8 v0 = *(const s16x8*)(qkv + (size_t)(row0 + sub * 32 + vj) * 3072 + vcol + 8 * va);
#pragma unroll
    for (int t2 = 0; t2 < 8; t2++) {
      int slot = 32 * vhi + 8 * va3 + (t2 ^ vxor);
      lds[0][4096 + sub * 2048 + vblk + slot * 8 + vef] = v0[t2];
    }
  }
  __syncthreads();

  f32x16 acc0 = {}, acc1 = {};
  float m2 = -1e30f, l_r = 0.f;
  const float THR = 8.f * 1.44269504088896f;   // defer-max, exp2 domain

  for (int jt = 0; jt < 32; jt++) {
    const int cur = jt & 1, nxt = cur ^ 1;
    const int jnext = (jt + 1) * 64;
    const bool pf = (jt < 31);

    // early prefetch issue: V global reads + K global_load_lds (tile t+1)
    s16x8 vs0, vs1;
    if (pf) {
      vs0 = *(const s16x8*)(qkv + (size_t)(row0 + jnext + vj) * 3072 + vcol + 8 * va);
      vs1 = *(const s16x8*)(qkv + (size_t)(row0 + jnext + 32 + vj) * 3072 + vcol + 8 * va);
#pragma unroll
      for (int sub = 0; sub < 2; sub++)
        gload_lds16(qkv + (size_t)(row0 + jnext + sub * 32 + l31) * 3072 + kcol +
                        16 * w + 8 * hi,
                    &lds[nxt][(sub * 4 + w) * 512]);
    }

    // S^T = mfma(K, Q) for both 32-key subtiles (q pre-scaled)
    f32x16 st0 = {}, st1 = {};
    const short* lc = &lds[cur][0];
#pragma unroll
    for (int s = 0; s < 4; s++) {
      s16x8 kf0 = *(const s16x8*)&lc[s * 512 + lane * 8];
      s16x8 kf1 = *(const s16x8*)&lc[(4 + s) * 512 + lane * 8];
      st0 = __builtin_amdgcn_mfma_f32_32x32x16_bf16(kf0, qf[s], st0, 0, 0, 0);
      st1 = __builtin_amdgcn_mfma_f32_32x32x16_bf16(kf1, qf[s], st1, 0, 0, 0);
    }

    // merged 64-key online softmax (exp2 domain)
    float pm = fmaxf(st0[0], st0[1]);
#pragma unroll
    for (int r = 2; r < 16; r++) pm = fmaxf(pm, st0[r]);
#pragma unroll
    for (int r = 0; r < 16; r++) pm = fmaxf(pm, st1[r]);
    pm = fmaxf(pm, __shfl_xor(pm, 32, 64));
    if (__any(pm > m2 + THR)) {
      float mn = fmaxf(m2, pm);
      float al = exp2f(m2 - mn);
      m2 = mn;
      l_r *= al;
#pragma unroll
      for (int r = 0; r < 16; r++) { acc0[r] *= al; acc1[r] *= al; }
    }
    float rs = 0.f;
#pragma unroll
    for (int r = 0; r < 16; r++) { st0[r] = exp2f(st0[r] - m2); rs += st0[r]; }
#pragma unroll
    for (int r = 0; r < 16; r++) { st1[r] = exp2f(st1[r] - m2); rs += st1[r]; }
    rs += __shfl_xor(rs, 32, 64);
    l_r += rs;

    // V scatter for t+1 (after softmax; overlapped loads have landed by now)
    if (pf) {
#pragma unroll
      for (int t2 = 0; t2 < 8; t2++) {
        int slot = 32 * vhi + 8 * va3 + (t2 ^ vxor);
        lds[nxt][4096 + vblk + slot * 8 + vef] = vs0[t2];
        lds[nxt][4096 + 2048 + vblk + slot * 8 + vef] = vs1[t2];
      }
    }

    // PV: build P^T B-frags in-register (cvt_pk + permlane32_swap), accumulate
    const short* lV = &lds[cur][4096];
#pragma unroll
    for (int sub = 0; sub < 2; sub++) {
      const float* p = sub ? (const float*)&st1 : (const float*)&st0;
#pragma unroll
      for (int ks = 0; ks < 2; ks++) {
        int x0, x1, y0, y1;
        asm("v_cvt_pk_bf16_f32 %0, %1, %2" : "=v"(x0) : "v"(p[8*ks+0]), "v"(p[8*ks+1]));
        asm("v_cvt_pk_bf16_f32 %0, %1, %2" : "=v"(x1) : "v"(p[8*ks+2]), "v"(p[8*ks+3]));
        asm("v_cvt_pk_bf16_f32 %0, %1, %2" : "=v"(y0) : "v"(p[8*ks+4]), "v"(p[8*ks+5]));
        asm("v_cvt_pk_bf16_f32 %0, %1, %2" : "=v"(y1) : "v"(p[8*ks+6]), "v"(p[8*ks+7]));
        // {w0,w2} = swap(x0,y0); {w1,w3} = swap(x1,y1)  (== round-4 select net)
        i32x2 s02 = __builtin_amdgcn_permlane32_swap(x0, y0, false, false);
        i32x2 s13 = __builtin_amdgcn_permlane32_swap(x1, y1, false, false);
        int4 paw; paw.x = s02[0]; paw.y = s13[0]; paw.z = s02[1]; paw.w = s13[1];
        s16x8 pa = __builtin_bit_cast(s16x8, paw);
        s16x8 v0 = *(const s16x8*)&lV[sub * 2048 + (ks * 2 + 0) * 512 + vslot_r];
        s16x8 v1 = *(const s16x8*)&lV[sub * 2048 + (ks * 2 + 1) * 512 + vslot_r];
        acc0 = __builtin_amdgcn_mfma_f32_32x32x16_bf16(v0, pa, acc0, 0, 0, 0);
        acc1 = __builtin_amdgcn_mfma_f32_32x32x16_bf16(v1, pa, acc1, 0, 0, 0);
      }
    }

    __syncthreads();   // drains vmcnt (K prefetch) + orders buffer swap
  }

  // epilogue: O[q][d] = O^T / l
  float inv = 1.f / l_r;
  const size_t rowoff = (size_t)(row0 + qt * 128 + w * 32 + l31) * 1024 + head * 64;
#pragma unroll
  for (int r = 0; r < 16; r++) {
    int dbase = (r & 3) + 8 * (r >> 2) + 4 * hi;
    aout[rowoff + dbase] = f2bf(acc0[r] * inv);
    aout[rowoff + 32 + dbase] = f2bf(acc1[r] * inv);
  }
}

// ---------- launch ----------
extern "C" void kernel_launch(void* const* d_in, const int* in_sizes, int n_in,
                              void* d_out, int out_size, void* d_ws, size_t ws_size,
                              hipStream_t stream) {
  const float* x    = (const float*)d_in[0];
  const float* Wq   = (const float*)d_in[1];
  const float* Wk   = (const float*)d_in[2];
  const float* Wv   = (const float*)d_in[3];
  const float* Wout = (const float*)d_in[4];
  const float* bout = (const float*)d_in[5];
  float* out = (float*)d_out;

  char* ws = (char*)d_ws;
  short* xb    = (short*)(ws);                        // 16 MB  [8192][1024]
  short* Wqkv  = (short*)(ws + (16ull << 20));        //  6 MB  [3072][1024]
  short* Woutb = (short*)(ws + (22ull << 20));        //  2 MB  [1024][1024]
  short* qkv   = (short*)(ws + (24ull << 20));        // 48 MB  [8192][3072]
  short* a_ws  = xb;                                  // alias: xb dead after GEMM1

  const float SCL = 0.125f * 1.44269504088896f;       // 1/sqrt(64) * log2(e)

  // fp32 -> bf16
  cvt_kernel<<<8192, 256, 0, stream>>>(x, xb, 2097152);
  cvt_kernel<<<1024, 256, 0, stream>>>(Wq, Wqkv, 262144);
  cvt_kernel<<<1024, 256, 0, stream>>>(Wk, Wqkv + 1048576, 262144);
  cvt_kernel<<<1024, 256, 0, stream>>>(Wv, Wqkv + 2097152, 262144);
  cvt_kernel<<<1024, 256, 0, stream>>>(Wout, Woutb, 262144);

  // qkv = xb @ [Wq;Wk;Wv]^T  (q cols pre-scaled by SCL in f32 epilogue)
  gemm_bt<0><<<64 * 24, 256, 0, stream>>>(xb, Wqkv, qkv, nullptr, 8192, 3072, 1024,
                                          SCL, 1024);

  // attention: 4 b * 16 heads * 16 q-tiles
  attn_kernel<<<1024, 256, 0, stream>>>(qkv, a_ws);

  // out = a @ Wout^T + bout  (fp32 out)
  gemm_bt<1><<<64 * 8, 256, 0, stream>>>(a_ws, Woutb, out, bout, 8192, 1024, 1024,
                                         1.f, 0);
}